// Round 6
// baseline (1965.815 us; speedup 1.0000x reference)
//
#include <hip/hip_runtime.h>
#include <hip/hip_bf16.h>

#define MM 2048
#define CC 64
#define NEG_EPS_INV (-10.0f)   // -1/EPS, EPS=0.1
#define NBLK 256               // persistent grid; capacity >= 256 blocks -> co-resident

// ---------------------------------------------------------------------------
// k_tr: seq2t[b][n][c] = feat2[b][c][n]   (64x64 LDS transpose tiles)
// ---------------------------------------------------------------------------
__global__ __launch_bounds__(256) void k_tr(const float* __restrict__ f2,
                                            float* __restrict__ s2t) {
    __shared__ float t[64 * 65];
    int bx = blockIdx.x;
    int b = bx >> 5, nc = bx & 31;
    int tid = threadIdx.x;
    int col = tid & 63, cp = tid >> 6;
    const size_t fbase = (size_t)b * CC * MM;
    for (int it = 0; it < 16; ++it) {
        int c = it * 4 + cp;
        t[c * 65 + col] = f2[fbase + (size_t)c * MM + nc * 64 + col];
    }
    __syncthreads();
    int w = tid >> 6, lane = tid & 63;
    for (int i = 0; i < 16; ++i) {
        int nn = w * 16 + i;
        s2t[((size_t)b * MM + nc * 64 + nn) * 64 + lane] = t[lane * 65 + nn];
    }
}

// ---------------------------------------------------------------------------
// k_build: K0[b][m][n] = -max(sq1[m]+sq2[n]-2*cross,0)/eps  AND K0T (transpose)
// grid: 2048 blocks (2 x 32 x 32), 256 threads
// ---------------------------------------------------------------------------
__global__ __launch_bounds__(256) void k_build(const float* __restrict__ f1,
                                               const float* __restrict__ f2,
                                               float* __restrict__ K0,
                                               float* __restrict__ K0T) {
    __shared__ float f1s[64 * 64];
    __shared__ float f2s[64 * 64];
    __shared__ float kt[64 * 65];
    __shared__ float sq1s[64], sq2s[64];
    int bx = blockIdx.x;
    int b = bx >> 10, mt = (bx >> 5) & 31, nt = bx & 31;
    int tid = threadIdx.x;
    int w = tid >> 6, lane = tid & 63;
    int col = tid & 63, cp = tid >> 6;
    const size_t fbase = (size_t)b * CC * MM;
    for (int it = 0; it < 16; ++it) {
        int c = it * 4 + cp;
        f1s[c * 64 + col] = f1[fbase + (size_t)c * MM + mt * 64 + col];
        f2s[c * 64 + col] = f2[fbase + (size_t)c * MM + nt * 64 + col];
    }
    __syncthreads();
    if (tid < 64) {
        float s = 0.f;
        for (int c = 0; c < 64; ++c) { float x = f1s[c * 64 + tid]; s = fmaf(x, x, s); }
        sq1s[tid] = s;
    } else if (tid < 128) {
        int n = tid - 64;
        float s = 0.f;
        for (int c = 0; c < 64; ++c) { float x = f2s[c * 64 + n]; s = fmaf(x, x, s); }
        sq2s[n] = s;
    }
    __syncthreads();
    float acc[16];
#pragma unroll
    for (int i = 0; i < 16; ++i) acc[i] = 0.f;
    for (int c = 0; c < 64; ++c) {
        float f2v = f2s[c * 64 + lane];
#pragma unroll
        for (int i = 0; i < 16; ++i)
            acc[i] = fmaf(f1s[c * 64 + w * 16 + i], f2v, acc[i]);
    }
    float sq2v = sq2s[lane];
    size_t kbase = ((size_t)b * MM + mt * 64 + w * 16) * MM + nt * 64 + lane;
#pragma unroll
    for (int i = 0; i < 16; ++i) {
        float r = sq1s[w * 16 + i] + sq2v - 2.f * acc[i];
        float kv = NEG_EPS_INV * fmaxf(r, 0.f);
        K0[kbase + (size_t)i * MM] = kv;
        kt[(w * 16 + i) * 65 + lane] = kv;
    }
    __syncthreads();
    size_t tbase = ((size_t)b * MM + nt * 64 + w * 16) * MM + mt * 64 + lane;
#pragma unroll
    for (int i = 0; i < 16; ++i)
        K0T[tbase + (size_t)i * MM] = kt[lane * 65 + (w * 16 + i)];
}

// ---------------------------------------------------------------------------
// gbar: one-shot-slot global barrier (proven working in R5). Release fence +
// device atomicAdd arrive; relaxed agent poll; acquire fence. Bounded spin.
// ---------------------------------------------------------------------------
__device__ __forceinline__ void gbar(int* bar, int slot, int tid) {
    __syncthreads();
    if (tid == 0) {
        __threadfence();                     // release (agent scope: L2 wb)
        atomicAdd(&bar[slot], 1);
        long guard = 0;
        while (__hip_atomic_load(&bar[slot], __ATOMIC_RELAXED,
                                 __HIP_MEMORY_SCOPE_AGENT) < NBLK &&
               ++guard < (1L << 25)) {
            __builtin_amdgcn_s_sleep(2);
        }
        __threadfence();                     // acquire (agent scope: L2 inv)
    }
    __syncthreads();
}

// LSE2: two max-shifted row-LSE updates (exactly Round-2 numerics).
// DST[row0+r] = -lse_i(K[r][i] + SRC[ci]),  ci = j*256 + lane*4 + k
#define LSE2(KA, KB, SRCP, DSTP)                                         \
    {                                                                    \
        float xl[32];                                                    \
        _Pragma("unroll")                                                \
        for (int j = 0; j < 8; ++j) {                                    \
            float4 t = ((const float4*)(SRCP))[j * 64 + lane];           \
            xl[4*j+0] = t.x; xl[4*j+1] = t.y;                            \
            xl[4*j+2] = t.z; xl[4*j+3] = t.w;                            \
        }                                                                \
        _Pragma("unroll")                                                \
        for (int r = 0; r < 2; ++r) {                                    \
            float mx = -3.0e38f;                                         \
            _Pragma("unroll")                                            \
            for (int i = 0; i < 32; ++i)                                 \
                mx = fmaxf(mx, (r == 0 ? KA[i] : KB[i]) + xl[i]);        \
            _Pragma("unroll")                                            \
            for (int off = 32; off >= 1; off >>= 1)                      \
                mx = fmaxf(mx, __shfl_xor(mx, off));                     \
            float s = 0.f;                                               \
            _Pragma("unroll")                                            \
            for (int i = 0; i < 32; ++i)                                 \
                s += __expf((r == 0 ? KA[i] : KB[i]) + xl[i] - mx);      \
            _Pragma("unroll")                                            \
            for (int off = 32; off >= 1; off >>= 1)                      \
                s += __shfl_xor(s, off);                                 \
            if (lane == 0) (DSTP)[row0 + r] = -(mx + __logf(s));         \
        }                                                                \
    }

// ---------------------------------------------------------------------------
// k_sink: persistent Sinkhorn, BOTH K0 rows and K0T rows in registers.
// 256 blocks x 8 waves x 2 rows = 4096 rows (and 4096 cols). Per iteration:
//   u = -lse_n(K0 + v)   [max-shifted, per-wave rows]   -> gbar
//   v = -lse_m(K0T + u)  [max-shifted, per-wave cols]   -> gbar
// Zero matrix memory traffic inside the loop; numerics == Round-2 (passed).
// ---------------------------------------------------------------------------
__global__ __launch_bounds__(512) void k_sink(const float* __restrict__ K0,
                                              const float* __restrict__ K0T,
                                              float* __restrict__ u,
                                              float* __restrict__ v,
                                              int* __restrict__ bar) {
    const int blk = blockIdx.x;
    const int b = blk >> 7, rg = blk & 127;
    const int tid = threadIdx.x;
    const int lane = tid & 63;
    const int w = tid >> 6;
    const int row0 = rg * 16 + w * 2;

    float kr0[32], kr1[32], kc0[32], kc1[32];
    {
        const float4* r0p = (const float4*)(K0 + ((size_t)b * MM + row0) * MM);
        const float4* r1p = (const float4*)(K0 + ((size_t)b * MM + row0 + 1) * MM);
        const float4* c0p = (const float4*)(K0T + ((size_t)b * MM + row0) * MM);
        const float4* c1p = (const float4*)(K0T + ((size_t)b * MM + row0 + 1) * MM);
#pragma unroll
        for (int j = 0; j < 8; ++j) {
            float4 a = r0p[j * 64 + lane];
            kr0[4*j+0] = a.x; kr0[4*j+1] = a.y; kr0[4*j+2] = a.z; kr0[4*j+3] = a.w;
            float4 c = r1p[j * 64 + lane];
            kr1[4*j+0] = c.x; kr1[4*j+1] = c.y; kr1[4*j+2] = c.z; kr1[4*j+3] = c.w;
            float4 d = c0p[j * 64 + lane];
            kc0[4*j+0] = d.x; kc0[4*j+1] = d.y; kc0[4*j+2] = d.z; kc0[4*j+3] = d.w;
            float4 e = c1p[j * 64 + lane];
            kc1[4*j+0] = e.x; kc1[4*j+1] = e.y; kc1[4*j+2] = e.z; kc1[4*j+3] = e.w;
        }
    }
    float* up = u + (size_t)b * MM;
    float* vp = v + (size_t)b * MM;

    for (int it = 0; it < 50; ++it) {
        LSE2(kr0, kr1, vp, up);      // u = -lse_n(K0 + v)
        gbar(bar, 2 * it, tid);
        LSE2(kc0, kc1, up, vp);      // v = -lse_m(K0T + u)
        gbar(bar, 2 * it + 1, tid);
    }
}

// ---------------------------------------------------------------------------
// k_fot: fot[b][m][c] += sum_n exp(K0+u+v) * seq2t[b][n][c]   (n-split, atomics)
// ---------------------------------------------------------------------------
__global__ __launch_bounds__(256) void k_fot(const float* __restrict__ K0,
                                             const float* __restrict__ u,
                                             const float* __restrict__ v,
                                             const float* __restrict__ s2t,
                                             float* __restrict__ fot) {
    extern __shared__ float plds[];  // [4 waves][512 n][8 r]
    int bx = blockIdx.x;
    int b = bx >> 8, mg = (bx >> 2) & 63, ns = bx & 3;
    int w = threadIdx.x >> 6, lane = threadIdx.x & 63;
    int m0 = mg * 32 + w * 8;
    float* pw = plds + w * 512 * 8;
    const float* vp = v + (size_t)b * MM + ns * 512;
#pragma unroll
    for (int r = 0; r < 8; ++r) {
        const float* krow = K0 + ((size_t)b * MM + m0 + r) * MM + ns * 512;
        float uv = u[(size_t)b * MM + m0 + r];
        for (int j = 0; j < 8; ++j) {
            int nn = j * 64 + lane;
            pw[nn * 8 + r] = __expf(krow[nn] + uv + vp[nn]);
        }
    }
    __syncthreads();
    float acc[8];
#pragma unroll
    for (int r = 0; r < 8; ++r) acc[r] = 0.f;
    const float* s2p = s2t + ((size_t)b * MM + ns * 512) * 64 + lane;
    for (int nn = 0; nn < 512; ++nn) {
        float s2 = s2p[(size_t)nn * 64];
        float4 p0 = *(const float4*)(pw + nn * 8);
        float4 p1 = *(const float4*)(pw + nn * 8 + 4);
        acc[0] = fmaf(p0.x, s2, acc[0]);
        acc[1] = fmaf(p0.y, s2, acc[1]);
        acc[2] = fmaf(p0.z, s2, acc[2]);
        acc[3] = fmaf(p0.w, s2, acc[3]);
        acc[4] = fmaf(p1.x, s2, acc[4]);
        acc[5] = fmaf(p1.y, s2, acc[5]);
        acc[6] = fmaf(p1.z, s2, acc[6]);
        acc[7] = fmaf(p1.w, s2, acc[7]);
    }
#pragma unroll
    for (int r = 0; r < 8; ++r)
        atomicAdd(&fot[((size_t)b * MM + m0 + r) * 64 + lane], acc[r]);
}

// ---------------------------------------------------------------------------
// k_gate: h=relu(W1@cat+b1); g=sigmoid(W2@h+b2); out=g*f1+(1-g)*fot
// ---------------------------------------------------------------------------
__global__ __launch_bounds__(256) void k_gate(const float* __restrict__ f1,
                                              const float* __restrict__ fot,
                                              const float* __restrict__ w1,
                                              const float* __restrict__ b1,
                                              const float* __restrict__ w2,
                                              const float* __restrict__ b2,
                                              float* __restrict__ out) {
    __shared__ float w1s[64 * 129];
    __shared__ float w2s[64 * 65];
    __shared__ float cats[4 * 128];
    __shared__ float hs[4 * 64];
    __shared__ float outs[64 * 5];
    int bx = blockIdx.x;
    int b = bx >> 9, mg = bx & 511;
    int tid = threadIdx.x;
    int w = tid >> 6, lane = tid & 63;
    int m = mg * 4 + w;
    for (int t = 0; t < 32; ++t) {
        int idx = t * 256 + tid;
        w1s[(idx >> 7) * 129 + (idx & 127)] = w1[idx];
    }
    for (int t = 0; t < 16; ++t) {
        int idx = t * 256 + tid;
        w2s[(idx >> 6) * 65 + (idx & 63)] = w2[idx];
    }
    float f1v = f1[(size_t)b * CC * MM + (size_t)lane * MM + m];
    float fov = fot[((size_t)b * MM + m) * 64 + lane];
    cats[w * 128 + lane] = f1v;
    cats[w * 128 + 64 + lane] = fov;
    __syncthreads();
    float hacc = b1[lane];
    for (int c = 0; c < 128; ++c)
        hacc = fmaf(w1s[lane * 129 + c], cats[w * 128 + c], hacc);
    hs[w * 64 + lane] = fmaxf(hacc, 0.f);
    __syncthreads();
    float g = b2[lane];
    for (int c = 0; c < 64; ++c)
        g = fmaf(w2s[lane * 65 + c], hs[w * 64 + c], g);
    g = 1.f / (1.f + __expf(-g));
    float fused = g * f1v + (1.f - g) * fov;
    outs[lane * 5 + w] = fused;
    __syncthreads();
    int o = tid >> 2, mi = tid & 3;
    out[(size_t)b * CC * MM + (size_t)o * MM + mg * 4 + mi] = outs[o * 5 + mi];
}

// ---------------------------------------------------------------------------
extern "C" void kernel_launch(void* const* d_in, const int* in_sizes, int n_in,
                              void* d_out, int out_size, void* d_ws, size_t ws_size,
                              hipStream_t stream) {
    const float* feat1 = (const float*)d_in[0];
    const float* feat2 = (const float*)d_in[1];
    const float* w1 = (const float*)d_in[2];
    const float* b1 = (const float*)d_in[3];
    const float* w2 = (const float*)d_in[4];
    const float* b2 = (const float*)d_in[5];
    float* out = (float*)d_out;
    float* ws = (float*)d_ws;

    // layout (floats): K0 | K0T | u | v | s2t | fot | bar   (~67.6 MB total)
    float* K0  = ws;                         // 8,388,608
    float* K0T = K0 + (size_t)8388608;       // 8,388,608
    float* u   = K0T + (size_t)8388608;      // 4,096
    float* v   = u + 4096;                   // 4,096
    float* s2t = v + 4096;                   // 262,144
    float* fot = s2t + 262144;               // 262,144
    int*   bar = (int*)(fot + 262144);       // 128 ints

    k_tr<<<64, 256, 0, stream>>>(feat2, s2t);
    k_build<<<2048, 256, 0, stream>>>(feat1, feat2, K0, K0T);
    hipMemsetAsync(v, 0, 16384, stream);
    hipMemsetAsync(fot, 0, 1048576, stream);
    hipMemsetAsync(bar, 0, 512, stream);

    k_sink<<<NBLK, 512, 0, stream>>>(K0, K0T, u, v, bar);

    k_fot<<<512, 256, 65536, stream>>>(K0, u, v, s2t, fot);
    k_gate<<<1024, 256, 0, stream>>>(feat1, fot, w1, b1, w2, b2, out);
}

// Round 7
// 1284.992 us; speedup vs baseline: 1.5298x; 1.5298x over previous
//
#include <hip/hip_runtime.h>
#include <hip/hip_bf16.h>

#define MM 2048
#define CC 64
#define NEG_EPS_INV (-10.0f)   // -1/EPS, EPS=0.1
#define NBLK 256               // persistent grid; 1 block/CU, all co-resident

// ---------------------------------------------------------------------------
// k_tr: seq2t[b][n][c] = feat2[b][c][n]   (64x64 LDS transpose tiles)
// ---------------------------------------------------------------------------
__global__ __launch_bounds__(256) void k_tr(const float* __restrict__ f2,
                                            float* __restrict__ s2t) {
    __shared__ float t[64 * 65];
    int bx = blockIdx.x;
    int b = bx >> 5, nc = bx & 31;
    int tid = threadIdx.x;
    int col = tid & 63, cp = tid >> 6;
    const size_t fbase = (size_t)b * CC * MM;
    for (int it = 0; it < 16; ++it) {
        int c = it * 4 + cp;
        t[c * 65 + col] = f2[fbase + (size_t)c * MM + nc * 64 + col];
    }
    __syncthreads();
    int w = tid >> 6, lane = tid & 63;
    for (int i = 0; i < 16; ++i) {
        int nn = w * 16 + i;
        s2t[((size_t)b * MM + nc * 64 + nn) * 64 + lane] = t[lane * 65 + nn];
    }
}

// ---------------------------------------------------------------------------
// k_build: K0[b][m][n] = -max(sq1[m]+sq2[n]-2*cross,0)/eps  AND K0T (transpose)
// ---------------------------------------------------------------------------
__global__ __launch_bounds__(256) void k_build(const float* __restrict__ f1,
                                               const float* __restrict__ f2,
                                               float* __restrict__ K0,
                                               float* __restrict__ K0T) {
    __shared__ float f1s[64 * 64];
    __shared__ float f2s[64 * 64];
    __shared__ float kt[64 * 65];
    __shared__ float sq1s[64], sq2s[64];
    int bx = blockIdx.x;
    int b = bx >> 10, mt = (bx >> 5) & 31, nt = bx & 31;
    int tid = threadIdx.x;
    int w = tid >> 6, lane = tid & 63;
    int col = tid & 63, cp = tid >> 6;
    const size_t fbase = (size_t)b * CC * MM;
    for (int it = 0; it < 16; ++it) {
        int c = it * 4 + cp;
        f1s[c * 64 + col] = f1[fbase + (size_t)c * MM + mt * 64 + col];
        f2s[c * 64 + col] = f2[fbase + (size_t)c * MM + nt * 64 + col];
    }
    __syncthreads();
    if (tid < 64) {
        float s = 0.f;
        for (int c = 0; c < 64; ++c) { float x = f1s[c * 64 + tid]; s = fmaf(x, x, s); }
        sq1s[tid] = s;
    } else if (tid < 128) {
        int n = tid - 64;
        float s = 0.f;
        for (int c = 0; c < 64; ++c) { float x = f2s[c * 64 + n]; s = fmaf(x, x, s); }
        sq2s[n] = s;
    }
    __syncthreads();
    float acc[16];
#pragma unroll
    for (int i = 0; i < 16; ++i) acc[i] = 0.f;
    for (int c = 0; c < 64; ++c) {
        float f2v = f2s[c * 64 + lane];
#pragma unroll
        for (int i = 0; i < 16; ++i)
            acc[i] = fmaf(f1s[c * 64 + w * 16 + i], f2v, acc[i]);
    }
    float sq2v = sq2s[lane];
    size_t kbase = ((size_t)b * MM + mt * 64 + w * 16) * MM + nt * 64 + lane;
#pragma unroll
    for (int i = 0; i < 16; ++i) {
        float r = sq1s[w * 16 + i] + sq2v - 2.f * acc[i];
        float kv = NEG_EPS_INV * fmaxf(r, 0.f);
        K0[kbase + (size_t)i * MM] = kv;
        kt[(w * 16 + i) * 65 + lane] = kv;
    }
    __syncthreads();
    size_t tbase = ((size_t)b * MM + nt * 64 + w * 16) * MM + mt * 64 + lane;
#pragma unroll
    for (int i = 0; i < 16; ++i)
        K0T[tbase + (size_t)i * MM] = kt[lane * 65 + (w * 16 + i)];
}

// ---------------------------------------------------------------------------
// Hierarchical per-batch barrier. 128 participants/batch.
// Counters padded to 256B (64 ints) so every line carries ONE counter.
// Arrive: sub (16 adds/line, 8 lines) -> root (8 adds) -> go (1 store).
// Fan-out: 8 sub-finishers poll go, then set gosub[g]; others poll gosub[g]
// (<=16 read-only pollers per line, zero RMW traffic on polled lines).
// idx = (slot*2 + b): one-shot slot per barrier instance (memset each call).
// ---------------------------------------------------------------------------
#define PAD 64
#define N_IDX 200   // 100 barriers x 2 batches
__device__ __forceinline__ void gbar(int* __restrict__ sub, int* __restrict__ root,
                                     int* __restrict__ go, int* __restrict__ gosub,
                                     int idx, int g, int tid) {
    __syncthreads();
    if (tid == 0) {
        __threadfence();                                   // release
        int old = atomicAdd(&sub[(idx * 8 + g) * PAD], 1);
        if (old == 15) {                                   // last of 16 in sub-group
            int old2 = atomicAdd(&root[idx * PAD], 1);
            if (old2 == 7) {                               // last sub-group
                atomicExch(&go[idx * PAD], 1);
            } else {
                long gu = 0;
                while (!__hip_atomic_load(&go[idx * PAD], __ATOMIC_RELAXED,
                                          __HIP_MEMORY_SCOPE_AGENT) &&
                       ++gu < (1L << 24))
                    __builtin_amdgcn_s_sleep(2);
            }
            atomicExch(&gosub[(idx * 8 + g) * PAD], 1);
        } else {
            long gu = 0;
            while (!__hip_atomic_load(&gosub[(idx * 8 + g) * PAD], __ATOMIC_RELAXED,
                                      __HIP_MEMORY_SCOPE_AGENT) &&
                   ++gu < (1L << 24))
                __builtin_amdgcn_s_sleep(8);
        }
        __threadfence();                                   // acquire
    }
    __syncthreads();
}

// LSE2: two max-shifted row-LSE updates (Round-2 numerics, verified passing).
#define LSE2(KA, KB, SRCP, DSTP)                                         \
    {                                                                    \
        float xl[32];                                                    \
        _Pragma("unroll")                                                \
        for (int j = 0; j < 8; ++j) {                                    \
            float4 t = ((const float4*)(SRCP))[j * 64 + lane];           \
            xl[4*j+0] = t.x; xl[4*j+1] = t.y;                            \
            xl[4*j+2] = t.z; xl[4*j+3] = t.w;                            \
        }                                                                \
        _Pragma("unroll")                                                \
        for (int r = 0; r < 2; ++r) {                                    \
            float mx = -3.0e38f;                                         \
            _Pragma("unroll")                                            \
            for (int i = 0; i < 32; ++i)                                 \
                mx = fmaxf(mx, (r == 0 ? KA[i] : KB[i]) + xl[i]);        \
            _Pragma("unroll")                                            \
            for (int off = 32; off >= 1; off >>= 1)                      \
                mx = fmaxf(mx, __shfl_xor(mx, off));                     \
            float s = 0.f;                                               \
            _Pragma("unroll")                                            \
            for (int i = 0; i < 32; ++i)                                 \
                s += __expf((r == 0 ? KA[i] : KB[i]) + xl[i] - mx);      \
            _Pragma("unroll")                                            \
            for (int off = 32; off >= 1; off >>= 1)                      \
                s += __shfl_xor(s, off);                                 \
            if (lane == 0) (DSTP)[row0 + r] = -(mx + __logf(s));         \
        }                                                                \
    }

// ---------------------------------------------------------------------------
// k_sink: persistent Sinkhorn, K0 rows AND K0T rows in registers.
// __launch_bounds__(512, 2): min 2 waves/EU -> VGPR cap >= 256/lane -> the
// 128 K-floats/lane stay in registers (R6's unhinted build spilled at 116).
// 256 blocks: b = blk>>7 (batches sync independently), 8 waves x 2 rows.
// ---------------------------------------------------------------------------
__global__ __launch_bounds__(512, 2) void k_sink(const float* __restrict__ K0,
                                                 const float* __restrict__ K0T,
                                                 float* __restrict__ u,
                                                 float* __restrict__ v,
                                                 int* __restrict__ barmem) {
    const int blk = blockIdx.x;
    const int b = blk >> 7, rg = blk & 127;
    const int g = rg >> 4;                 // 8 sub-groups of 16 blocks
    const int tid = threadIdx.x;
    const int lane = tid & 63;
    const int w = tid >> 6;
    const int row0 = rg * 16 + w * 2;

    int* sub   = barmem;
    int* root  = sub + N_IDX * 8 * PAD;
    int* go    = root + N_IDX * PAD;
    int* gosub = go + N_IDX * PAD;

    float kr0[32], kr1[32], kc0[32], kc1[32];
    {
        const float4* r0p = (const float4*)(K0 + ((size_t)b * MM + row0) * MM);
        const float4* r1p = (const float4*)(K0 + ((size_t)b * MM + row0 + 1) * MM);
        const float4* c0p = (const float4*)(K0T + ((size_t)b * MM + row0) * MM);
        const float4* c1p = (const float4*)(K0T + ((size_t)b * MM + row0 + 1) * MM);
#pragma unroll
        for (int j = 0; j < 8; ++j) {
            float4 a = r0p[j * 64 + lane];
            kr0[4*j+0] = a.x; kr0[4*j+1] = a.y; kr0[4*j+2] = a.z; kr0[4*j+3] = a.w;
            float4 c = r1p[j * 64 + lane];
            kr1[4*j+0] = c.x; kr1[4*j+1] = c.y; kr1[4*j+2] = c.z; kr1[4*j+3] = c.w;
            float4 d = c0p[j * 64 + lane];
            kc0[4*j+0] = d.x; kc0[4*j+1] = d.y; kc0[4*j+2] = d.z; kc0[4*j+3] = d.w;
            float4 e = c1p[j * 64 + lane];
            kc1[4*j+0] = e.x; kc1[4*j+1] = e.y; kc1[4*j+2] = e.z; kc1[4*j+3] = e.w;
        }
    }
    float* up = u + (size_t)b * MM;
    float* vp = v + (size_t)b * MM;

    for (int it = 0; it < 50; ++it) {
        LSE2(kr0, kr1, vp, up);                        // u = -lse_n(K0 + v)
        gbar(sub, root, go, gosub, (4 * it + 0) + b, g, tid);
        LSE2(kc0, kc1, up, vp);                        // v = -lse_m(K0T + u)
        gbar(sub, root, go, gosub, (4 * it + 2) + b, g, tid);
    }
}

// ---------------------------------------------------------------------------
// k_fot: fot[b][m][c] += sum_n exp(K0+u+v) * seq2t[b][n][c]   (n-split, atomics)
// ---------------------------------------------------------------------------
__global__ __launch_bounds__(256) void k_fot(const float* __restrict__ K0,
                                             const float* __restrict__ u,
                                             const float* __restrict__ v,
                                             const float* __restrict__ s2t,
                                             float* __restrict__ fot) {
    extern __shared__ float plds[];  // [4 waves][512 n][8 r]
    int bx = blockIdx.x;
    int b = bx >> 8, mg = (bx >> 2) & 63, ns = bx & 3;
    int w = threadIdx.x >> 6, lane = threadIdx.x & 63;
    int m0 = mg * 32 + w * 8;
    float* pw = plds + w * 512 * 8;
    const float* vp = v + (size_t)b * MM + ns * 512;
#pragma unroll
    for (int r = 0; r < 8; ++r) {
        const float* krow = K0 + ((size_t)b * MM + m0 + r) * MM + ns * 512;
        float uv = u[(size_t)b * MM + m0 + r];
        for (int j = 0; j < 8; ++j) {
            int nn = j * 64 + lane;
            pw[nn * 8 + r] = __expf(krow[nn] + uv + vp[nn]);
        }
    }
    __syncthreads();
    float acc[8];
#pragma unroll
    for (int r = 0; r < 8; ++r) acc[r] = 0.f;
    const float* s2p = s2t + ((size_t)b * MM + ns * 512) * 64 + lane;
    for (int nn = 0; nn < 512; ++nn) {
        float s2 = s2p[(size_t)nn * 64];
        float4 p0 = *(const float4*)(pw + nn * 8);
        float4 p1 = *(const float4*)(pw + nn * 8 + 4);
        acc[0] = fmaf(p0.x, s2, acc[0]);
        acc[1] = fmaf(p0.y, s2, acc[1]);
        acc[2] = fmaf(p0.z, s2, acc[2]);
        acc[3] = fmaf(p0.w, s2, acc[3]);
        acc[4] = fmaf(p1.x, s2, acc[4]);
        acc[5] = fmaf(p1.y, s2, acc[5]);
        acc[6] = fmaf(p1.z, s2, acc[6]);
        acc[7] = fmaf(p1.w, s2, acc[7]);
    }
#pragma unroll
    for (int r = 0; r < 8; ++r)
        atomicAdd(&fot[((size_t)b * MM + m0 + r) * 64 + lane], acc[r]);
}

// ---------------------------------------------------------------------------
// k_gate: h=relu(W1@cat+b1); g=sigmoid(W2@h+b2); out=g*f1+(1-g)*fot
// ---------------------------------------------------------------------------
__global__ __launch_bounds__(256) void k_gate(const float* __restrict__ f1,
                                              const float* __restrict__ fot,
                                              const float* __restrict__ w1,
                                              const float* __restrict__ b1,
                                              const float* __restrict__ w2,
                                              const float* __restrict__ b2,
                                              float* __restrict__ out) {
    __shared__ float w1s[64 * 129];
    __shared__ float w2s[64 * 65];
    __shared__ float cats[4 * 128];
    __shared__ float hs[4 * 64];
    __shared__ float outs[64 * 5];
    int bx = blockIdx.x;
    int b = bx >> 9, mg = bx & 511;
    int tid = threadIdx.x;
    int w = tid >> 6, lane = tid & 63;
    int m = mg * 4 + w;
    for (int t = 0; t < 32; ++t) {
        int idx = t * 256 + tid;
        w1s[(idx >> 7) * 129 + (idx & 127)] = w1[idx];
    }
    for (int t = 0; t < 16; ++t) {
        int idx = t * 256 + tid;
        w2s[(idx >> 6) * 65 + (idx & 63)] = w2[idx];
    }
    float f1v = f1[(size_t)b * CC * MM + (size_t)lane * MM + m];
    float fov = fot[((size_t)b * MM + m) * 64 + lane];
    cats[w * 128 + lane] = f1v;
    cats[w * 128 + 64 + lane] = fov;
    __syncthreads();
    float hacc = b1[lane];
    for (int c = 0; c < 128; ++c)
        hacc = fmaf(w1s[lane * 129 + c], cats[w * 128 + c], hacc);
    hs[w * 64 + lane] = fmaxf(hacc, 0.f);
    __syncthreads();
    float g = b2[lane];
    for (int c = 0; c < 64; ++c)
        g = fmaf(w2s[lane * 65 + c], hs[w * 64 + c], g);
    g = 1.f / (1.f + __expf(-g));
    float fused = g * f1v + (1.f - g) * fov;
    outs[lane * 5 + w] = fused;
    __syncthreads();
    int o = tid >> 2, mi = tid & 3;
    out[(size_t)b * CC * MM + (size_t)o * MM + mg * 4 + mi] = outs[o * 5 + mi];
}

// ---------------------------------------------------------------------------
extern "C" void kernel_launch(void* const* d_in, const int* in_sizes, int n_in,
                              void* d_out, int out_size, void* d_ws, size_t ws_size,
                              hipStream_t stream) {
    const float* feat1 = (const float*)d_in[0];
    const float* feat2 = (const float*)d_in[1];
    const float* w1 = (const float*)d_in[2];
    const float* b1 = (const float*)d_in[3];
    const float* w2 = (const float*)d_in[4];
    const float* b2 = (const float*)d_in[5];
    float* out = (float*)d_out;
    float* ws = (float*)d_ws;

    // layout (floats): K0 | K0T | u | v | s2t | fot | barmem
    float* K0  = ws;                         // 8,388,608
    float* K0T = K0 + (size_t)8388608;       // 8,388,608
    float* u   = K0T + (size_t)8388608;      // 4,096
    float* v   = u + 4096;                   // 4,096
    float* s2t = v + 4096;                   // 262,144
    float* fot = s2t + 262144;               // 262,144
    int*   bar = (int*)(fot + 262144);
    // barmem ints: sub 200*8*64 + root 200*64 + go 200*64 + gosub 200*8*64
    const size_t barInts = (size_t)N_IDX * 8 * PAD * 2 + (size_t)N_IDX * PAD * 2;

    k_tr<<<64, 256, 0, stream>>>(feat2, s2t);
    k_build<<<2048, 256, 0, stream>>>(feat1, feat2, K0, K0T);
    hipMemsetAsync(v, 0, 16384, stream);
    hipMemsetAsync(fot, 0, 1048576, stream);
    hipMemsetAsync(bar, 0, barInts * sizeof(int), stream);

    k_sink<<<NBLK, 512, 0, stream>>>(K0, K0T, u, v, bar);

    k_fot<<<512, 256, 65536, stream>>>(K0, u, v, s2t, fot);
    k_gate<<<1024, 256, 0, stream>>>(feat1, fot, w1, b1, w2, b2, out);
}